// Round 6
// baseline (423.209 us; speedup 1.0000x reference)
//
#include <hip/hip_runtime.h>
#include <math.h>

// ---------------------------------------------------------------------------
// AdaptiveWindowAttention — round 11: gemm_qkv = 256^2 deep pipeline built
// from the two HW-verified halves: r7's superrow-XOR K-half-plane LDS layout
// (0 bank conflicts measured) + r9's 8-wave 128x64/wave geometry, natural
// block order (n%8 XCD L2 partition — r10 taught us not to swizzle), and an
// audited counted-vmcnt ring (VM8/VM4, never 0 in loop; every staged group
// has >=2 phases to land). gemm_out = proven 128^2 natural-order core.
// B=2 S=2048 EMB=2048 H=16 D=128; window in [64,256]
// ---------------------------------------------------------------------------

#define S_LEN 2048
#define EMB 2048
#define HEADS 16
#define HDIM 128
#define NT 20          // attn: 320-key span = NT*16
#define PSTR 336       // attn: P row stride in f16 (320 + 16 pad)

typedef _Float16 f16x8 __attribute__((ext_vector_type(8)));
typedef _Float16 f16x4 __attribute__((ext_vector_type(4)));
typedef float f32x4 __attribute__((ext_vector_type(4)));

__device__ __forceinline__ void gld16(const void* g, void* l) {
    __builtin_amdgcn_global_load_lds(
        (const __attribute__((address_space(1))) unsigned int*)g,
        (__attribute__((address_space(3))) unsigned int*)l, 16, 0, 0);
}

// ---------------- rope tables (cos,sin interleaved), f32 ----------------
__global__ void rope_table(float2* __restrict__ cstab) {
    int s = blockIdx.x;
    int d = threadIdx.x;
    int j = d & 63;
    float inv = exp2f(-13.287712379549449f * (float)j * (1.0f / 64.0f));
    float ang = (float)s * inv;
    cstab[s * HDIM + d] = make_float2(cosf(ang), sinf(ang));
}

// ---------------- batch stats + fused x->f16 (float4, 4 cols/thread) --------
__global__ __launch_bounds__(256) void col_reduce(const float* __restrict__ x,
                                                  float* __restrict__ xmean_acc,
                                                  double* __restrict__ scal,
                                                  _Float16* __restrict__ x16) {
    int b = blockIdx.z;
    int cg = blockIdx.x;
    int sg = blockIdx.y;
    int e4 = cg * 256 + threadIdx.x;
    const size_t base = ((size_t)b * S_LEN + sg * 32) * EMB;
    const float4* xb = (const float4*)(x + base) + e4;
    f16x4* xo = (f16x4*)(x16 + base) + e4;
    double cs0 = 0.0, cs1 = 0.0, cs2 = 0.0, cs3 = 0.0;
    double cq = 0.0;
    for (int s = 0; s < 32; ++s) {
        float4 v = xb[(size_t)s * (EMB / 4)];
        f16x4 o;
        o.x = (_Float16)v.x; o.y = (_Float16)v.y;
        o.z = (_Float16)v.z; o.w = (_Float16)v.w;
        xo[(size_t)s * (EMB / 4)] = o;
        cs0 += v.x; cs1 += v.y; cs2 += v.z; cs3 += v.w;
        cq += (double)v.x * v.x + (double)v.y * v.y +
              (double)v.z * v.z + (double)v.w * v.w;
    }
    float* xm = xmean_acc + b * EMB + e4 * 4;
    atomicAdd(xm + 0, (float)cs0);
    atomicAdd(xm + 1, (float)cs1);
    atomicAdd(xm + 2, (float)cs2);
    atomicAdd(xm + 3, (float)cs3);
    __shared__ double rs[256], rq[256];
    rs[threadIdx.x] = cs0 + cs1 + cs2 + cs3;
    rq[threadIdx.x] = cq;
    __syncthreads();
    for (int off = 128; off > 0; off >>= 1) {
        if (threadIdx.x < off) {
            rs[threadIdx.x] += rs[threadIdx.x + off];
            rq[threadIdx.x] += rq[threadIdx.x + off];
        }
        __syncthreads();
    }
    if (threadIdx.x == 0) {
        atomicAdd(&scal[b], rs[0]);
        atomicAdd(&scal[2 + b], rq[0]);
    }
}

__global__ __launch_bounds__(256) void hidden_kernel(const float* __restrict__ xmean_acc,
                                                     const float* __restrict__ wc1,
                                                     float* __restrict__ hidden) {
    int j = blockIdx.x;
    int b = blockIdx.y;
    const float* xm = xmean_acc + b * EMB;
    const float* wr = wc1 + (size_t)j * EMB;
    double acc = 0.0;
    for (int k = threadIdx.x; k < EMB; k += 256)
        acc += (double)xm[k] * (double)wr[k];
    __shared__ double red[256];
    red[threadIdx.x] = acc;
    __syncthreads();
    for (int off = 128; off > 0; off >>= 1) {
        if (threadIdx.x < off) red[threadIdx.x] += red[threadIdx.x + off];
        __syncthreads();
    }
    if (threadIdx.x == 0) {
        double z = red[0] * (1.0 / 2048.0);
        hidden[b * 512 + j] = (float)(z / (1.0 + exp(-z)));
    }
}

__global__ __launch_bounds__(512) void window_kernel(const float* __restrict__ hidden,
                                                     const float* __restrict__ wc2,
                                                     const double* __restrict__ scal,
                                                     int* __restrict__ wout) {
    __shared__ double red[512];
    __shared__ double wfs[2];
    for (int b = 0; b < 2; ++b) {
        red[threadIdx.x] = (double)hidden[b * 512 + threadIdx.x] * (double)wc2[threadIdx.x];
        __syncthreads();
        for (int off = 256; off > 0; off >>= 1) {
            if (threadIdx.x < off) red[threadIdx.x] += red[threadIdx.x + off];
            __syncthreads();
        }
        if (threadIdx.x == 0) {
            double pre = red[0];
            double learned = 1.0 / (1.0 + exp(-pre));
            const double N = (double)S_LEN * (double)EMB;
            double sum = scal[b], sq = scal[2 + b];
            double var = (sq - sum * sum / N) / (N - 1.0);
            double vn = 1.0 / (1.0 + exp(-(var * 10.0 - 5.0)));
            double comp = 0.5 * (vn + learned);
            wfs[b] = 64.0 + comp * 192.0;
        }
        __syncthreads();
    }
    if (threadIdx.x == 0) {
        float wf = (float)(0.5 * (wfs[0] + wfs[1]));
        int w = (int)wf;
        if (w > S_LEN) w = S_LEN;
        if (w < 64) w = 64;
        *wout = w;
    }
}

// ---------------- f32 -> f16 conversion (both weights, one launch) ----------
#define NQKV4 3145728
#define NOUT4 1048576
__global__ __launch_bounds__(256) void cvt_weights(const float* __restrict__ wqkv,
                                                   const float* __restrict__ wout,
                                                   _Float16* __restrict__ d_qkv,
                                                   _Float16* __restrict__ d_out) {
    int i = blockIdx.x * 256 + threadIdx.x;
    const float4* s;
    f16x4* d;
    if (i < NQKV4) {
        s = (const float4*)wqkv + i;
        d = (f16x4*)d_qkv + i;
    } else {
        s = (const float4*)wout + (i - NQKV4);
        d = (f16x4*)d_out + (i - NQKV4);
    }
    float4 v = *s;
    f16x4 o;
    o.x = (_Float16)v.x; o.y = (_Float16)v.y;
    o.z = (_Float16)v.z; o.w = (_Float16)v.w;
    *d = o;
}

// ---------------------------------------------------------------------------
// gemm_qkv: 256x256 tile, BK=64, 512 thr / 8 waves (2M x 4N), per-wave 128x64.
// LDS: K-half planes Ap/Bp[buf][h] of 256 rows x 32 k, superrow-XOR layout
// (r7-verified, 0 conflicts): superrow sr=row>>1 is 128B = 8 chunks of 16B;
// logical chunk c=(row&1)*4+(k>>3) stored at slot c^(sr&7). global_load_lds
// writes linearly; the XOR is pre-applied to the per-lane GLOBAL src address.
// Ring (audited): phase(t,h0) stages both halves of tile t+1 (8 gld), ends
// vmcnt(8); phase(t,h1) ends vmcnt(4). Every group lands >=2 phases before
// its first read; vmcnt never 0 in the main loop.
// ---------------------------------------------------------------------------

#define STG(bufc, hc, kofs)                                                 \
    gld16(aS0 + (kofs), &Ap[bufc][hc][wv * 512]);                           \
    gld16(aS1 + (kofs), &Ap[bufc][hc][4096 + wv * 512]);                    \
    gld16(bS0 + (kofs), &Bp[bufc][hc][wv * 512]);                           \
    gld16(bS1 + (kofs), &Bp[bufc][hc][4096 + wv * 512]);

#define VM8 asm volatile("s_waitcnt vmcnt(8)" ::: "memory");
#define VM4 asm volatile("s_waitcnt vmcnt(4)" ::: "memory");
#define VM0 asm volatile("s_waitcnt vmcnt(0)" ::: "memory");
#define VMN

#define PH(bufc, hc, VM, ...)                                               \
    {                                                                       \
        f16x8 af[8], bf[4];                                                 \
        _Pragma("unroll")                                                   \
        for (int j_ = 0; j_ < 4; ++j_)                                      \
            bf[j_] = *(const f16x8*)&Bp[bufc][hc][bbase + j_ * 512];        \
        _Pragma("unroll")                                                   \
        for (int i_ = 0; i_ < 8; ++i_)                                      \
            af[i_] = *(const f16x8*)&Ap[bufc][hc][abase + i_ * 512];        \
        __VA_ARGS__                                                         \
        __builtin_amdgcn_sched_barrier(0);                                  \
        __builtin_amdgcn_s_barrier();                                       \
        asm volatile("s_waitcnt lgkmcnt(0)" ::: "memory");                  \
        __builtin_amdgcn_sched_barrier(0);                                  \
        __builtin_amdgcn_s_setprio(1);                                      \
        _Pragma("unroll")                                                   \
        for (int i_ = 0; i_ < 8; ++i_)                                      \
            _Pragma("unroll")                                               \
            for (int j_ = 0; j_ < 4; ++j_)                                  \
                acc[i_][j_] = __builtin_amdgcn_mfma_f32_16x16x32_f16(       \
                    af[i_], bf[j_], acc[i_][j_], 0, 0, 0);                  \
        __builtin_amdgcn_s_setprio(0);                                      \
        __builtin_amdgcn_sched_barrier(0);                                  \
        VM                                                                  \
        __builtin_amdgcn_s_barrier();                                       \
        __builtin_amdgcn_sched_barrier(0);                                  \
    }

__global__ __launch_bounds__(512, 2) void gemm_qkv_f16(const _Float16* __restrict__ An,
                                                       const _Float16* __restrict__ Wn,
                                                       _Float16* __restrict__ q16,
                                                       _Float16* __restrict__ k16,
                                                       _Float16* __restrict__ vt,
                                                       const float2* __restrict__ cstab) {
    __shared__ __align__(16) _Float16 Ap[2][2][8192];   // [buf][khalf][256x32]
    __shared__ __align__(16) _Float16 Bp[2][2][8192];
    const int tid = threadIdx.x;
    const int lane = tid & 63;
    const int wv = tid >> 6;
    const int wm = wv >> 2;        // 0..1
    const int wn = wv & 3;         // 0..3
    const int m0 = blockIdx.y * 256;   // natural order: XCD = bx%8 -> n-slice
    const int n0 = blockIdx.x * 256;
    // staging source, pre-swizzled for the superrow-XOR layout (r7-verified):
    // lane l writes LDS slot (sr = wv*8 + (l>>3), cs = l&7); content must be
    // logical chunk g = cs ^ (sr&7): row = wv*16 + 2*(l>>3) + (g>>2), k-chunk g&3.
    const int g = (lane & 7) ^ (lane >> 3);
    const int rb = 2 * (lane >> 3) + (g >> 2);
    const int kq = (g & 3) * 8;
    const _Float16* aS0 = An + (size_t)(m0 + wv * 16 + rb) * EMB + kq;
    const _Float16* aS1 = aS0 + (size_t)128 * EMB;
    const _Float16* bS0 = Wn + (size_t)(n0 + wv * 16 + rb) * EMB + kq;
    const _Float16* bS1 = bS0 + (size_t)128 * EMB;
    // fragment read offsets (f16 units): row = base + i*16 + frow, k-chunk fgrp
    // -> sr = base/2 + i*8 + srl, chunk slot = (((frow&1)<<2)+fgrp) ^ srl
    const int frow = lane & 15;
    const int fgrp = lane >> 4;
    const int srl = frow >> 1;
    const int cst = ((((frow & 1) << 2) + fgrp) ^ srl);
    const int abase = (wm * 64 + srl) * 64 + cst * 8;
    const int bbase = (wn * 32 + srl) * 64 + cst * 8;
    f32x4 acc[8][4] = {};

    // prologue: stage tiles 0 and 1 fully; force tile 0 landed
    STG(0, 0, 0) STG(0, 1, 32) STG(1, 0, 64) STG(1, 1, 96)
    VM8
    __builtin_amdgcn_s_barrier();
    __builtin_amdgcn_sched_barrier(0);

    // tile 0 (buf0), no stages
    PH(0, 0, VM8)
    PH(0, 1, VM4)
    // tiles 1..30: stage t+1 during phase h0
    for (int it = 0; it < 15; ++it) {
        PH(1, 0, VM8, STG(0, 0, 128) STG(0, 1, 160))
        PH(1, 1, VM4)
        PH(0, 0, VM8, STG(1, 0, 192) STG(1, 1, 224))
        PH(0, 1, VM4)
        aS0 += 128; aS1 += 128; bS0 += 128; bS1 += 128;
    }
    // tile 31 (buf1): drain
    PH(1, 0, VM0)
    PH(1, 1, VMN)

    // ---- epilogue (r9-verified): rope fused q/k; v transposed ----
    const int colbase = lane & 15;
    const int rowoff = fgrp * 4;
    const int nb = n0 + wn * 64;
    const int which = nb >> 11;
    const int h = (nb >> 7) & 15;
    const int d0 = nb & 127;               // 0 or 64
    if (which == 2) {
#pragma unroll
        for (int i = 0; i < 8; ++i) {
#pragma unroll
            for (int j = 0; j < 4; ++j) {
                const int d = d0 + j * 16 + colbase;
                int m = m0 + wm * 128 + i * 16 + rowoff;  // 4 consecutive rows
                int b = m >> 11, s = m & 2047;
                f16x4 o;
#pragma unroll
                for (int r = 0; r < 4; ++r) o[r] = (_Float16)acc[i][j][r];
                *(f16x4*)&vt[(((size_t)b * HEADS + h) * HDIM + d) * S_LEN + s] = o;
            }
        }
    } else {
        _Float16* dst = which == 0 ? q16 : k16;
        const float sgn = (colbase & 1) ? 1.f : -1.f;   // rotate_half sign
#pragma unroll
        for (int i = 0; i < 8; ++i) {
#pragma unroll
            for (int j = 0; j < 4; ++j) {
                const int d = d0 + j * 16 + colbase;
#pragma unroll
                for (int r = 0; r < 4; ++r) {
                    int m = m0 + wm * 128 + i * 16 + rowoff + r;
                    int b = m >> 11, s = m & 2047;
                    float a = acc[i][j][r];
                    float p = __shfl_xor(a, 1, 64);      // partner: d^1, same s
                    float2 cs = cstab[(size_t)s * HDIM + d];
                    float o = fmaf(a, cs.x, sgn * p * cs.y);
                    dst[(((size_t)b * HEADS + h) * S_LEN + s) * HDIM + d] = (_Float16)o;
                }
            }
        }
    }
}

// ---------------- 128^2 GEMM core (proven round-6, natural order) -----------
#define GEMM_PROLOGUE(An, Wn)                                                   \
    __shared__ _Float16 As[128 * 64];                                           \
    __shared__ _Float16 Bs[128 * 64];                                           \
    const int tid = threadIdx.x;                                                \
    const int lane = tid & 63;                                                  \
    const int wv = tid >> 6;                                                    \
    const int wm = wv >> 1, wn = wv & 1;                                        \
    const int m0 = blockIdx.y * 128;                                            \
    const int n0 = blockIdx.x * 128;                                            \
    const int lrow = lane >> 3;                            /* 0..7 */           \
    const int lchk = (lane & 7) ^ lrow;                    /* swizzled src */   \
    const int srow = wv * 32 + lrow;                                            \
    const _Float16* agp = An + (size_t)(m0 + srow) * EMB + lchk * 8;            \
    const _Float16* bgp = Wn + (size_t)(n0 + srow) * EMB + lchk * 8;            \
    _Float16* al = &As[wv * 32 * 64];                                           \
    _Float16* bl = &Bs[wv * 32 * 64];                                           \
    const int frow = lane & 15;                                                 \
    const int fgrp = lane >> 4;                                                 \
    f32x4 acc[4][4] = {};                                                       \
    for (int k0 = 0; k0 < EMB; k0 += 64) {                                      \
        __syncthreads();                                                        \
        _Pragma("unroll")                                                       \
        for (int t = 0; t < 4; ++t) {                                           \
            gld16(agp + (size_t)t * 8 * EMB, al + t * 8 * 64);                  \
            gld16(bgp + (size_t)t * 8 * EMB, bl + t * 8 * 64);                  \
        }                                                                       \
        agp += 64; bgp += 64;                                                   \
        __syncthreads();                                                        \
        _Pragma("unroll")                                                       \
        for (int ks = 0; ks < 2; ++ks) {                                        \
            f16x8 af[4], bf[4];                                                 \
            _Pragma("unroll")                                                   \
            for (int i = 0; i < 4; ++i)                                         \
                af[i] = *(const f16x8*)&As[(wm * 64 + i * 16 + frow) * 64 +     \
                                           (((ks * 4 + fgrp) ^ (frow & 7)) * 8)]; \
            _Pragma("unroll")                                                   \
            for (int j = 0; j < 4; ++j)                                         \
                bf[j] = *(const f16x8*)&Bs[(wn * 64 + j * 16 + frow) * 64 +     \
                                           (((ks * 4 + fgrp) ^ (frow & 7)) * 8)]; \
            _Pragma("unroll")                                                   \
            for (int i = 0; i < 4; ++i)                                         \
                _Pragma("unroll")                                               \
                for (int j = 0; j < 4; ++j)                                     \
                    acc[i][j] = __builtin_amdgcn_mfma_f32_16x16x32_f16(         \
                        af[i], bf[j], acc[i][j], 0, 0, 0);                      \
        }                                                                       \
    }                                                                           \
    const int colbase = lane & 15;                                              \
    const int rowoff = (lane >> 4) * 4;

__global__ __launch_bounds__(256) void gemm_out_f16(const _Float16* __restrict__ An,
                                                    const _Float16* __restrict__ Wn,
                                                    float* __restrict__ C) {
    GEMM_PROLOGUE(An, Wn)
#pragma unroll
    for (int i = 0; i < 4; ++i) {
#pragma unroll
        for (int j = 0; j < 4; ++j) {
            const int n = n0 + wn * 64 + j * 16 + colbase;
#pragma unroll
            for (int r = 0; r < 4; ++r) {
                int m = m0 + wm * 64 + i * 16 + rowoff + r;
                C[(size_t)m * EMB + n] = acc[i][j][r];
            }
        }
    }
}

// ---------------- MFMA attention (per-wave exact tile bounds) ----------------
__global__ __launch_bounds__(256) void attn_mfma(const _Float16* __restrict__ q16,
                                                 const _Float16* __restrict__ k16,
                                                 const _Float16* __restrict__ v16t,
                                                 _Float16* __restrict__ ob,
                                                 const int* __restrict__ wptr) {
    const int q0 = blockIdx.x * 64;
    const int h = blockIdx.y;
    const int b = blockIdx.z;
    const int tid = threadIdx.x;
    const int lane = tid & 63;
    const int wv = tid >> 6;
    const int w = *wptr;

    __shared__ _Float16 Pl[4][16 * PSTR];
    _Float16* Pw = Pl[wv];

    const int kstart = q0 - 256;
    int ntlo_w = ((257 - w) >> 4) + wv;
    int ntlo_n = q0 < 256 ? ((256 - q0) >> 4) : 0;
    const int lo = ntlo_w > ntlo_n ? ntlo_w : ntlo_n;
    const int hi = wv + 17;
    const int pvlo = lo >> 1;
    const int pvhi = (hi + 1) >> 1;
    const int plo2 = pvlo << 1;
    const int phi2 = pvhi << 1;

    const int frow = lane & 15;
    const int fgrp = lane >> 4;
    const int fcol = fgrp * 8;

    const size_t bh = (size_t)b * HEADS + h;
    const _Float16* Qp = q16 + (bh * S_LEN + q0 + wv * 16 + frow) * HDIM + fcol;
    const _Float16* Kb = k16 + bh * S_LEN * HDIM;
    const _Float16* Vt = v16t + bh * HDIM * S_LEN;

    f16x8 aq[4];
#pragma unroll
    for (int ks = 0; ks < 4; ++ks) aq[ks] = *(const f16x8*)(Qp + ks * 32);

    // ---- QK^T (only alive tiles) ----
    f32x4 accs[NT];
#pragma unroll
    for (int nt = 0; nt < NT; ++nt) accs[nt] = (f32x4){0.f, 0.f, 0.f, 0.f};
#pragma unroll
    for (int nt = 0; nt < NT; ++nt) {
        if (nt < lo || nt >= hi) continue;
        int krow = kstart + nt * 16 + frow;
        if (krow < 0) krow = 0;
        const _Float16* kp = Kb + (size_t)krow * HDIM + fcol;
#pragma unroll
        for (int ks = 0; ks < 4; ++ks) {
            f16x8 bk = *(const f16x8*)(kp + ks * 32);
            accs[nt] = __builtin_amdgcn_mfma_f32_16x16x32_f16(aq[ks], bk, accs[nt], 0, 0, 0);
        }
    }

    // ---- mask + scale; row max ----
    const int qrow = fgrp * 4;
    const int qabs = q0 + wv * 16 + qrow;
    const float scale = 0.08838834764831845f;
    float mx[4] = {-INFINITY, -INFINITY, -INFINITY, -INFINITY};
#pragma unroll
    for (int nt = 0; nt < NT; ++nt) {
        if (nt < lo || nt >= hi) continue;
        int key = kstart + nt * 16 + frow;
#pragma unroll
        for (int r = 0; r < 4; ++r) {
            int rel = (qabs + r) - key;
            bool keep = (key >= 0) && (rel >= 0) && (rel < w);
            float s = keep ? accs[nt][r] * scale : -INFINITY;
            accs[nt][r] = s;
            mx[r] = fmaxf(mx[r], s);
        }
    }
#pragma unroll
    for (int r = 0; r < 4; ++r) {
        float m = mx[r];
#pragma unroll
        for (int off = 1; off < 16; off <<= 1)
            m = fmaxf(m, __shfl_xor(m, off, 64));
        mx[r] = m;
    }

    // ---- exp, row sum, store P (zero-fill dead tiles within PV span) ----
    float ls[4] = {0.f, 0.f, 0.f, 0.f};
#pragma unroll
    for (int nt = 0; nt < NT; ++nt) {
        if (nt < plo2 || nt >= phi2) continue;
        const bool alive = (nt >= lo) && (nt < hi);
#pragma unroll
        for (int r = 0; r < 4; ++r) {
            float p = alive ? __expf(accs[nt][r] - mx[r]) : 0.f;
            ls[r] += p;
            Pw[(qrow + r) * PSTR + nt * 16 + frow] = (_Float16)p;
        }
    }
    float inv[4];
#pragma unroll
    for (int r = 0; r < 4; ++r) {
        float l = ls[r];
#pragma unroll
        for (int off = 1; off < 16; off <<= 1)
            l += __shfl_xor(l, off, 64);
        inv[r] = 1.f / l;
    }

    // ---- PV (only alive 32-key tiles) ----
    f32x4 acco[8];
#pragma unroll
    for (int jt = 0; jt < 8; ++jt) acco[jt] = (f32x4){0.f, 0.f, 0.f, 0.f};
    const _Float16* Pr = &Pl[wv][frow * PSTR];
#pragma unroll
    for (int kp = 0; kp < 10; ++kp) {
        if (kp < pvlo || kp >= pvhi) continue;
        f16x8 ap = *(const f16x8*)(Pr + kp * 32 + fcol);
        int kv = kstart + kp * 32 + fcol;
        if (kv < 0) kv = 0;
#pragma unroll
        for (int jt = 0; jt < 8; ++jt) {
            f16x8 bv = *(const f16x8*)(Vt + (size_t)(jt * 16 + frow) * S_LEN + kv);
            acco[jt] = __builtin_amdgcn_mfma_f32_16x16x32_f16(ap, bv, acco[jt], 0, 0, 0);
        }
    }

    // ---- store O (b, s, h*128+d) f16 ----
#pragma unroll
    for (int jt = 0; jt < 8; ++jt) {
#pragma unroll
        for (int r = 0; r < 4; ++r) {
            int s = qabs + r;
            ob[((size_t)b * S_LEN + s) * EMB + h * HDIM + jt * 16 + frow] =
                (_Float16)(acco[jt][r] * inv[r]);
        }
    }
}

// ---------------------------------------------------------------------------
extern "C" void kernel_launch(void* const* d_in, const int* in_sizes, int n_in,
                              void* d_out, int out_size, void* d_ws, size_t ws_size,
                              hipStream_t stream) {
    const float* x     = (const float*)d_in[0];
    const float* w_qkv = (const float*)d_in[1];
    const float* w_out = (const float*)d_in[2];
    const float* w_c1  = (const float*)d_in[3];
    const float* w_c2  = (const float*)d_in[4];
    float* out = (float*)d_out;
    char* ws = (char*)d_ws;

    // ws layout (bytes). ao16 aliases wqkv16 (dead after gemm_qkv).
    double*    scal   = (double*)(ws + 0);
    int*       win    = (int*)(ws + 64);
    float*     xmean  = (float*)(ws + 128);
    float*     hidden = (float*)(ws + 16640);
    float2*    cstab  = (float2*)(ws + 32768);       // 2 MB
    _Float16*  x16    = (_Float16*)(ws + 4194304);   // 16.8 MB
    _Float16*  wqkv16 = (_Float16*)(ws + 20971520);  // 25.2 MB
    _Float16*  ao16   = (_Float16*)(ws + 20971520);  // alias
    _Float16*  v16t   = (_Float16*)(ws + 46137344);  // 16.8 MB
    _Float16*  q16    = (_Float16*)(ws + 62914560);  // 16.8 MB
    _Float16*  k16    = (_Float16*)(ws + 79691776);  // 16.8 MB
    _Float16*  wout16 = (_Float16*)(ws + 96468992);  // 8.4 MB

    hipMemsetAsync(d_ws, 0, 32768, stream);

    rope_table<<<dim3(S_LEN), dim3(HDIM), 0, stream>>>(cstab);
    col_reduce<<<dim3(2, 64, 2), dim3(256), 0, stream>>>(x, xmean, scal, x16);
    hidden_kernel<<<dim3(512, 2), dim3(256), 0, stream>>>(xmean, w_c1, hidden);
    window_kernel<<<dim3(1), dim3(512), 0, stream>>>(hidden, w_c2, scal, win);

    cvt_weights<<<dim3((NQKV4 + NOUT4) / 256), dim3(256), 0, stream>>>(
        w_qkv, w_out, wqkv16, wout16);

    gemm_qkv_f16<<<dim3(24, 16), dim3(512), 0, stream>>>(x16, wqkv16, q16, k16, v16t, cstab);
    attn_mfma<<<dim3(32, HEADS, 2), dim3(256), 0, stream>>>(q16, k16, v16t, ao16, win);
    gemm_out_f16<<<dim3(16, 32), dim3(256), 0, stream>>>(ao16, wout16, out);
}

// Round 8
// 382.157 us; speedup vs baseline: 1.1074x; 1.1074x over previous
//
#include <hip/hip_runtime.h>
#include <math.h>

// ---------------------------------------------------------------------------
// AdaptiveWindowAttention — round 13: round-12's coalesced LDS-transposed
// qkv epilogue, but RoPE computed bit-identically to the passing round-8
// path (f32 acc + shfl partner, single f16 rounding) BEFORE the transpose —
// r12's absmax failure (0.0757 vs 0.0725) was the extra f16 pre-rounding of
// q/k. attn: setprio(1) around QK^T/PV MFMA clusters (guide T5, +4-7% attn).
// GEMM K-loop = proven round-6/8 core, natural block order.
// B=2 S=2048 EMB=2048 H=16 D=128; window in [64,256]
// ---------------------------------------------------------------------------

#define S_LEN 2048
#define EMB 2048
#define HEADS 16
#define HDIM 128
#define NT 20          // attn: 320-key span = NT*16
#define PSTR 336       // attn: P row stride in f16 (320 + 16 pad)

typedef _Float16 f16x8 __attribute__((ext_vector_type(8)));
typedef _Float16 f16x4 __attribute__((ext_vector_type(4)));
typedef float f32x4 __attribute__((ext_vector_type(4)));

__device__ __forceinline__ void gld16(const void* g, void* l) {
    __builtin_amdgcn_global_load_lds(
        (const __attribute__((address_space(1))) unsigned int*)g,
        (__attribute__((address_space(3))) unsigned int*)l, 16, 0, 0);
}

// ---------------- rope tables (cos,sin interleaved), f32 ----------------
__global__ void rope_table(float2* __restrict__ cstab) {
    int s = blockIdx.x;
    int d = threadIdx.x;
    int j = d & 63;
    float inv = exp2f(-13.287712379549449f * (float)j * (1.0f / 64.0f));
    float ang = (float)s * inv;
    cstab[s * HDIM + d] = make_float2(cosf(ang), sinf(ang));
}

// ---------------- batch stats + fused x->f16 (float4, 4 cols/thread) --------
__global__ __launch_bounds__(256) void col_reduce(const float* __restrict__ x,
                                                  float* __restrict__ xmean_acc,
                                                  double* __restrict__ scal,
                                                  _Float16* __restrict__ x16) {
    int b = blockIdx.z;
    int cg = blockIdx.x;
    int sg = blockIdx.y;
    int e4 = cg * 256 + threadIdx.x;
    const size_t base = ((size_t)b * S_LEN + sg * 32) * EMB;
    const float4* xb = (const float4*)(x + base) + e4;
    f16x4* xo = (f16x4*)(x16 + base) + e4;
    double cs0 = 0.0, cs1 = 0.0, cs2 = 0.0, cs3 = 0.0;
    double cq = 0.0;
    for (int s = 0; s < 32; ++s) {
        float4 v = xb[(size_t)s * (EMB / 4)];
        f16x4 o;
        o.x = (_Float16)v.x; o.y = (_Float16)v.y;
        o.z = (_Float16)v.z; o.w = (_Float16)v.w;
        xo[(size_t)s * (EMB / 4)] = o;
        cs0 += v.x; cs1 += v.y; cs2 += v.z; cs3 += v.w;
        cq += (double)v.x * v.x + (double)v.y * v.y +
              (double)v.z * v.z + (double)v.w * v.w;
    }
    float* xm = xmean_acc + b * EMB + e4 * 4;
    atomicAdd(xm + 0, (float)cs0);
    atomicAdd(xm + 1, (float)cs1);
    atomicAdd(xm + 2, (float)cs2);
    atomicAdd(xm + 3, (float)cs3);
    __shared__ double rs[256], rq[256];
    rs[threadIdx.x] = cs0 + cs1 + cs2 + cs3;
    rq[threadIdx.x] = cq;
    __syncthreads();
    for (int off = 128; off > 0; off >>= 1) {
        if (threadIdx.x < off) {
            rs[threadIdx.x] += rs[threadIdx.x + off];
            rq[threadIdx.x] += rq[threadIdx.x + off];
        }
        __syncthreads();
    }
    if (threadIdx.x == 0) {
        atomicAdd(&scal[b], rs[0]);
        atomicAdd(&scal[2 + b], rq[0]);
    }
}

__global__ __launch_bounds__(256) void hidden_kernel(const float* __restrict__ xmean_acc,
                                                     const float* __restrict__ wc1,
                                                     float* __restrict__ hidden) {
    int j = blockIdx.x;
    int b = blockIdx.y;
    const float* xm = xmean_acc + b * EMB;
    const float* wr = wc1 + (size_t)j * EMB;
    double acc = 0.0;
    for (int k = threadIdx.x; k < EMB; k += 256)
        acc += (double)xm[k] * (double)wr[k];
    __shared__ double red[256];
    red[threadIdx.x] = acc;
    __syncthreads();
    for (int off = 128; off > 0; off >>= 1) {
        if (threadIdx.x < off) red[threadIdx.x] += red[threadIdx.x + off];
        __syncthreads();
    }
    if (threadIdx.x == 0) {
        double z = red[0] * (1.0 / 2048.0);
        hidden[b * 512 + j] = (float)(z / (1.0 + exp(-z)));
    }
}

__global__ __launch_bounds__(512) void window_kernel(const float* __restrict__ hidden,
                                                     const float* __restrict__ wc2,
                                                     const double* __restrict__ scal,
                                                     int* __restrict__ wout) {
    __shared__ double red[512];
    __shared__ double wfs[2];
    for (int b = 0; b < 2; ++b) {
        red[threadIdx.x] = (double)hidden[b * 512 + threadIdx.x] * (double)wc2[threadIdx.x];
        __syncthreads();
        for (int off = 256; off > 0; off >>= 1) {
            if (threadIdx.x < off) red[threadIdx.x] += red[threadIdx.x + off];
            __syncthreads();
        }
        if (threadIdx.x == 0) {
            double pre = red[0];
            double learned = 1.0 / (1.0 + exp(-pre));
            const double N = (double)S_LEN * (double)EMB;
            double sum = scal[b], sq = scal[2 + b];
            double var = (sq - sum * sum / N) / (N - 1.0);
            double vn = 1.0 / (1.0 + exp(-(var * 10.0 - 5.0)));
            double comp = 0.5 * (vn + learned);
            wfs[b] = 64.0 + comp * 192.0;
        }
        __syncthreads();
    }
    if (threadIdx.x == 0) {
        float wf = (float)(0.5 * (wfs[0] + wfs[1]));
        int w = (int)wf;
        if (w > S_LEN) w = S_LEN;
        if (w < 64) w = 64;
        *wout = w;
    }
}

// ---------------- f32 -> f16 conversion (both weights, one launch) ----------
#define NQKV4 3145728
#define NOUT4 1048576
__global__ __launch_bounds__(256) void cvt_weights(const float* __restrict__ wqkv,
                                                   const float* __restrict__ wout,
                                                   _Float16* __restrict__ d_qkv,
                                                   _Float16* __restrict__ d_out) {
    int i = blockIdx.x * 256 + threadIdx.x;
    const float4* s;
    f16x4* d;
    if (i < NQKV4) {
        s = (const float4*)wqkv + i;
        d = (f16x4*)d_qkv + i;
    } else {
        s = (const float4*)wout + (i - NQKV4);
        d = (f16x4*)d_out + (i - NQKV4);
    }
    float4 v = *s;
    f16x4 o;
    o.x = (_Float16)v.x; o.y = (_Float16)v.y;
    o.z = (_Float16)v.z; o.w = (_Float16)v.w;
    *d = o;
}

// ---------------- shared K-loop body (round-6/8 proven, natural order) ------
#define GEMM_KLOOP(An, Wn)                                                      \
    const int tid = threadIdx.x;                                                \
    const int lane = tid & 63;                                                  \
    const int wv = tid >> 6;                                                    \
    const int wm = wv >> 1, wn = wv & 1;                                        \
    const int m0 = blockIdx.y * 128;                                            \
    const int n0 = blockIdx.x * 128;                                            \
    const int lrow = lane >> 3;                            /* 0..7 */           \
    const int lchk = (lane & 7) ^ lrow;                    /* swizzled src */   \
    const int srow = wv * 32 + lrow;                                            \
    const _Float16* agp = An + (size_t)(m0 + srow) * EMB + lchk * 8;            \
    const _Float16* bgp = Wn + (size_t)(n0 + srow) * EMB + lchk * 8;            \
    _Float16* al = &As[wv * 32 * 64];                                           \
    _Float16* bl = &Bs[wv * 32 * 64];                                           \
    const int frow = lane & 15;                                                 \
    const int fgrp = lane >> 4;                                                 \
    f32x4 acc[4][4] = {};                                                       \
    for (int k0 = 0; k0 < EMB; k0 += 64) {                                      \
        __syncthreads();                                                        \
        _Pragma("unroll")                                                       \
        for (int t = 0; t < 4; ++t) {                                           \
            gld16(agp + (size_t)t * 8 * EMB, al + t * 8 * 64);                  \
            gld16(bgp + (size_t)t * 8 * EMB, bl + t * 8 * 64);                  \
        }                                                                       \
        agp += 64; bgp += 64;                                                   \
        __syncthreads();                                                        \
        _Pragma("unroll")                                                       \
        for (int ks = 0; ks < 2; ++ks) {                                        \
            f16x8 af[4], bf[4];                                                 \
            _Pragma("unroll")                                                   \
            for (int i = 0; i < 4; ++i)                                         \
                af[i] = *(const f16x8*)&As[(wm * 64 + i * 16 + frow) * 64 +     \
                                           (((ks * 4 + fgrp) ^ (frow & 7)) * 8)]; \
            _Pragma("unroll")                                                   \
            for (int j = 0; j < 4; ++j)                                         \
                bf[j] = *(const f16x8*)&Bs[(wn * 64 + j * 16 + frow) * 64 +     \
                                           (((ks * 4 + fgrp) ^ (frow & 7)) * 8)]; \
            _Pragma("unroll")                                                   \
            for (int i = 0; i < 4; ++i)                                         \
                _Pragma("unroll")                                               \
                for (int j = 0; j < 4; ++j)                                     \
                    acc[i][j] = __builtin_amdgcn_mfma_f32_16x16x32_f16(         \
                        af[i], bf[j], acc[i][j], 0, 0, 0);                      \
        }                                                                       \
    }                                                                           \
    const int colbase = lane & 15;                                              \
    const int rowoff = (lane >> 4) * 4;

// qkv: K-loop + epilogue. RoPE in f32 (shfl partner, exactly round-8's
// arithmetic, single f16 rounding), THEN f16 LDS transpose (exact) for
// coalesced 16B stores. Per-wave 64x64 f16 tile, stride 72 (144B).
__global__ __launch_bounds__(256) void gemm_qkv_f16(const _Float16* __restrict__ An,
                                                    const _Float16* __restrict__ Wn,
                                                    _Float16* __restrict__ q16,
                                                    _Float16* __restrict__ k16,
                                                    _Float16* __restrict__ vt,
                                                    const float2* __restrict__ cstab) {
    __shared__ __align__(16) _Float16 SMEM[18432];   // 36 KB
    _Float16* As = SMEM;
    _Float16* Bs = SMEM + 8192;
    GEMM_KLOOP(An, Wn)

    __syncthreads();                       // all waves done reading As/Bs
    _Float16* T = SMEM + wv * 4608;        // this wave's 64x64 (stride-72) tile
    const int which = n0 >> 11;            // 0=q 1=k 2=v
    const int h = (n0 >> 7) & 15;
    const int mwb = m0 + wm * 64;          // wave's first output row
    const int b = mwb >> 11;               // batch constant per block
    const int sbase = mwb & 2047;

    if (which == 2) {
        // ---- V: [d][s] tile, then coalesced rows along s (exact f16) ----
#pragma unroll
        for (int i = 0; i < 4; ++i) {
#pragma unroll
            for (int j = 0; j < 4; ++j) {
                f16x4 o;
#pragma unroll
                for (int r = 0; r < 4; ++r) o[r] = (_Float16)acc[i][j][r];
                *(f16x4*)&T[(j * 16 + colbase) * 72 + i * 16 + rowoff] = o;
            }
        }
        asm volatile("s_waitcnt lgkmcnt(0)" ::: "memory");
        __builtin_amdgcn_sched_barrier(0);
        const int dl = lane >> 3;          // 0..7
        const int s8 = (lane & 7) * 8;
#pragma unroll
        for (int t = 0; t < 8; ++t) {
            const int d_loc = t * 8 + dl;
            f16x8 v = *(const f16x8*)&T[d_loc * 72 + s8];
            const int d = wn * 64 + d_loc;
            *(f16x8*)&vt[(((size_t)b * HEADS + h) * HDIM + d) * S_LEN + sbase + s8] = v;
        }
    } else {
        // ---- Q/K: rope in f32 (round-8 arithmetic), f16 into [s][d] tile ----
        _Float16* dst = which == 0 ? q16 : k16;
        const float sgn = (colbase & 1) ? 1.f : -1.f;   // rotate_half sign
#pragma unroll
        for (int i = 0; i < 4; ++i) {
#pragma unroll
            for (int j = 0; j < 4; ++j) {
                const int d = wn * 64 + j * 16 + colbase;
#pragma unroll
                for (int r = 0; r < 4; ++r) {
                    const int s = sbase + i * 16 + rowoff + r;
                    float a = acc[i][j][r];
                    float p = __shfl_xor(a, 1, 64);      // partner: d^1, same s
                    float2 cs = cstab[(size_t)s * HDIM + d];
                    float o = fmaf(a, cs.x, sgn * p * cs.y);
                    T[(i * 16 + rowoff + r) * 72 + j * 16 + colbase] = (_Float16)o;
                }
            }
        }
        asm volatile("s_waitcnt lgkmcnt(0)" ::: "memory");
        __builtin_amdgcn_sched_barrier(0);
        const int sl = lane >> 3;          // 0..7
        const int d8 = (lane & 7) * 8;
        const int dd = wn * 64 + d8;
#pragma unroll
        for (int t = 0; t < 8; ++t) {
            const int s_loc = t * 8 + sl;
            f16x8 v = *(const f16x8*)&T[s_loc * 72 + d8];
            const int s = sbase + s_loc;
            *(f16x8*)&dst[(((size_t)b * HEADS + h) * S_LEN + s) * HDIM + dd] = v;
        }
    }
}

__global__ __launch_bounds__(256) void gemm_out_f16(const _Float16* __restrict__ An,
                                                    const _Float16* __restrict__ Wn,
                                                    float* __restrict__ C) {
    __shared__ _Float16 As[128 * 64];
    __shared__ _Float16 Bs[128 * 64];
    GEMM_KLOOP(An, Wn)
#pragma unroll
    for (int i = 0; i < 4; ++i) {
#pragma unroll
        for (int j = 0; j < 4; ++j) {
            const int n = n0 + wn * 64 + j * 16 + colbase;
#pragma unroll
            for (int r = 0; r < 4; ++r) {
                int m = m0 + wm * 64 + i * 16 + rowoff + r;
                C[(size_t)m * EMB + n] = acc[i][j][r];
            }
        }
    }
}

// ---------------- MFMA attention (per-wave exact tile bounds) ----------------
__global__ __launch_bounds__(256) void attn_mfma(const _Float16* __restrict__ q16,
                                                 const _Float16* __restrict__ k16,
                                                 const _Float16* __restrict__ v16t,
                                                 _Float16* __restrict__ ob,
                                                 const int* __restrict__ wptr) {
    const int q0 = blockIdx.x * 64;
    const int h = blockIdx.y;
    const int b = blockIdx.z;
    const int tid = threadIdx.x;
    const int lane = tid & 63;
    const int wv = tid >> 6;
    const int w = *wptr;

    __shared__ _Float16 Pl[4][16 * PSTR];
    _Float16* Pw = Pl[wv];

    const int kstart = q0 - 256;
    int ntlo_w = ((257 - w) >> 4) + wv;
    int ntlo_n = q0 < 256 ? ((256 - q0) >> 4) : 0;
    const int lo = ntlo_w > ntlo_n ? ntlo_w : ntlo_n;
    const int hi = wv + 17;
    const int pvlo = lo >> 1;
    const int pvhi = (hi + 1) >> 1;
    const int plo2 = pvlo << 1;
    const int phi2 = pvhi << 1;

    const int frow = lane & 15;
    const int fgrp = lane >> 4;
    const int fcol = fgrp * 8;

    const size_t bh = (size_t)b * HEADS + h;
    const _Float16* Qp = q16 + (bh * S_LEN + q0 + wv * 16 + frow) * HDIM + fcol;
    const _Float16* Kb = k16 + bh * S_LEN * HDIM;
    const _Float16* Vt = v16t + bh * HDIM * S_LEN;

    f16x8 aq[4];
#pragma unroll
    for (int ks = 0; ks < 4; ++ks) aq[ks] = *(const f16x8*)(Qp + ks * 32);

    // ---- QK^T (only alive tiles; setprio around MFMA cluster) ----
    f32x4 accs[NT];
#pragma unroll
    for (int nt = 0; nt < NT; ++nt) accs[nt] = (f32x4){0.f, 0.f, 0.f, 0.f};
    __builtin_amdgcn_s_setprio(1);
#pragma unroll
    for (int nt = 0; nt < NT; ++nt) {
        if (nt < lo || nt >= hi) continue;
        int krow = kstart + nt * 16 + frow;
        if (krow < 0) krow = 0;
        const _Float16* kp = Kb + (size_t)krow * HDIM + fcol;
#pragma unroll
        for (int ks = 0; ks < 4; ++ks) {
            f16x8 bk = *(const f16x8*)(kp + ks * 32);
            accs[nt] = __builtin_amdgcn_mfma_f32_16x16x32_f16(aq[ks], bk, accs[nt], 0, 0, 0);
        }
    }
    __builtin_amdgcn_s_setprio(0);

    // ---- mask + scale; row max ----
    const int qrow = fgrp * 4;
    const int qabs = q0 + wv * 16 + qrow;
    const float scale = 0.08838834764831845f;
    float mx[4] = {-INFINITY, -INFINITY, -INFINITY, -INFINITY};
#pragma unroll
    for (int nt = 0; nt < NT; ++nt) {
        if (nt < lo || nt >= hi) continue;
        int key = kstart + nt * 16 + frow;
#pragma unroll
        for (int r = 0; r < 4; ++r) {
            int rel = (qabs + r) - key;
            bool keep = (key >= 0) && (rel >= 0) && (rel < w);
            float s = keep ? accs[nt][r] * scale : -INFINITY;
            accs[nt][r] = s;
            mx[r] = fmaxf(mx[r], s);
        }
    }
#pragma unroll
    for (int r = 0; r < 4; ++r) {
        float m = mx[r];
#pragma unroll
        for (int off = 1; off < 16; off <<= 1)
            m = fmaxf(m, __shfl_xor(m, off, 64));
        mx[r] = m;
    }

    // ---- exp, row sum, store P (zero-fill dead tiles within PV span) ----
    float ls[4] = {0.f, 0.f, 0.f, 0.f};
#pragma unroll
    for (int nt = 0; nt < NT; ++nt) {
        if (nt < plo2 || nt >= phi2) continue;
        const bool alive = (nt >= lo) && (nt < hi);
#pragma unroll
        for (int r = 0; r < 4; ++r) {
            float p = alive ? __expf(accs[nt][r] - mx[r]) : 0.f;
            ls[r] += p;
            Pw[(qrow + r) * PSTR + nt * 16 + frow] = (_Float16)p;
        }
    }
    float inv[4];
#pragma unroll
    for (int r = 0; r < 4; ++r) {
        float l = ls[r];
#pragma unroll
        for (int off = 1; off < 16; off <<= 1)
            l += __shfl_xor(l, off, 64);
        inv[r] = 1.f / l;
    }

    // ---- PV (only alive 32-key tiles; setprio around MFMA cluster) ----
    f32x4 acco[8];
#pragma unroll
    for (int jt = 0; jt < 8; ++jt) acco[jt] = (f32x4){0.f, 0.f, 0.f, 0.f};
    const _Float16* Pr = &Pl[wv][frow * PSTR];
    __builtin_amdgcn_s_setprio(1);
#pragma unroll
    for (int kp = 0; kp < 10; ++kp) {
        if (kp < pvlo || kp >= pvhi) continue;
        f16x8 ap = *(const f16x8*)(Pr + kp * 32 + fcol);
        int kv = kstart + kp * 32 + fcol;
        if (kv < 0) kv = 0;
#pragma unroll
        for (int jt = 0; jt < 8; ++jt) {
            f16x8 bv = *(const f16x8*)(Vt + (size_t)(jt * 16 + frow) * S_LEN + kv);
            acco[jt] = __builtin_amdgcn_mfma_f32_16x16x32_f16(ap, bv, acco[jt], 0, 0, 0);
        }
    }
    __builtin_amdgcn_s_setprio(0);

    // ---- store O (b, s, h*128+d) f16 ----
#pragma unroll
    for (int jt = 0; jt < 8; ++jt) {
#pragma unroll
        for (int r = 0; r < 4; ++r) {
            int s = qabs + r;
            ob[((size_t)b * S_LEN + s) * EMB + h * HDIM + jt * 16 + frow] =
                (_Float16)(acco[jt][r] * inv[r]);
        }
    }
}

// ---------------------------------------------------------------------------
extern "C" void kernel_launch(void* const* d_in, const int* in_sizes, int n_in,
                              void* d_out, int out_size, void* d_ws, size_t ws_size,
                              hipStream_t stream) {
    const float* x     = (const float*)d_in[0];
    const float* w_qkv = (const float*)d_in[1];
    const float* w_out = (const float*)d_in[2];
    const float* w_c1  = (const float*)d_in[3];
    const float* w_c2  = (const float*)d_in[4];
    float* out = (float*)d_out;
    char* ws = (char*)d_ws;

    // ws layout (bytes). ao16 aliases wqkv16 (dead after gemm_qkv).
    double*    scal   = (double*)(ws + 0);
    int*       win    = (int*)(ws + 64);
    float*     xmean  = (float*)(ws + 128);
    float*     hidden = (float*)(ws + 16640);
    float2*    cstab  = (float2*)(ws + 32768);       // 2 MB
    _Float16*  x16    = (_Float16*)(ws + 4194304);   // 16.8 MB
    _Float16*  wqkv16 = (_Float16*)(ws + 20971520);  // 25.2 MB
    _Float16*  ao16   = (_Float16*)(ws + 20971520);  // alias
    _Float16*  v16t   = (_Float16*)(ws + 46137344);  // 16.8 MB
    _Float16*  q16    = (_Float16*)(ws + 62914560);  // 16.8 MB
    _Float16*  k16    = (_Float16*)(ws + 79691776);  // 16.8 MB
    _Float16*  wout16 = (_Float16*)(ws + 96468992);  // 8.4 MB

    hipMemsetAsync(d_ws, 0, 32768, stream);

    rope_table<<<dim3(S_LEN), dim3(HDIM), 0, stream>>>(cstab);
    col_reduce<<<dim3(2, 64, 2), dim3(256), 0, stream>>>(x, xmean, scal, x16);
    hidden_kernel<<<dim3(512, 2), dim3(256), 0, stream>>>(xmean, w_c1, hidden);
    window_kernel<<<dim3(1), dim3(512), 0, stream>>>(hidden, w_c2, scal, win);

    cvt_weights<<<dim3((NQKV4 + NOUT4) / 256), dim3(256), 0, stream>>>(
        w_qkv, w_out, wqkv16, wout16);

    gemm_qkv_f16<<<dim3(48, 32), dim3(256), 0, stream>>>(x16, wqkv16, q16, k16, v16t, cstab);
    attn_mfma<<<dim3(32, HEADS, 2), dim3(256), 0, stream>>>(q16, k16, v16t, ao16, win);
    gemm_out_f16<<<dim3(16, 32), dim3(256), 0, stream>>>(ao16, wout16, out);
}